// Round 3
// baseline (237.030 us; speedup 1.0000x reference)
//
#include <hip/hip_runtime.h>

// Problem constants (match reference)
#define V_ 100000
#define D_ 256
#define M_ 4096
#define C_ 4096
#define L_ 32
#define ROWS_MEMS (M_ + 1)          // 4097 rows in mems_enc (mems + xs_emb)
#define NTASK (1 + M_ + 1 + C_)     // 8194 encode row-tasks
#define NCHUNK 16                   // K2 row chunks (256 rows each, last +1)

__device__ __forceinline__ float wave_allreduce_sum(float v) {
    #pragma unroll
    for (int off = 32; off >= 1; off >>= 1) v += __shfl_xor(v, off, 64);
    return v;
}

// ---------------------------------------------------------------------------
// K1: encode all 8194 rows (one wave per row, 4 rows/block) and, for the
// 4097 mems_enc rows, fuse dot(row, xs) / norms / exp(cos) -> att[i].
// cos in [-1,1] so exp without max-subtraction is numerically safe.
// ---------------------------------------------------------------------------
__global__ __launch_bounds__(256) void encode_att(
    const int* __restrict__ xs, const int* __restrict__ mems,
    const int* __restrict__ ys, const int* __restrict__ cands,
    const float* __restrict__ lt, const float* __restrict__ freqs,
    float* __restrict__ enc,      // [4097, 256]; row 4096 = xs_emb
    float* __restrict__ att,      // [4097] unnormalized exp(cos)
    float* __restrict__ out_ys)   // d_out second half: [4097, 256]
{
    const int wave = threadIdx.x >> 6;
    const int lane = threadIdx.x & 63;
    const int rt = blockIdx.x * 4 + wave;
    if (rt >= NTASK) return;
    const int d0 = lane * 4;                // 64 lanes x 4 dims = 256

    const int* tok_ptr; float* dst; int ai = -1;
    if (rt == 0) {                          // xs -> enc row 4096
        tok_ptr = xs;  dst = enc + (size_t)M_ * D_;  ai = M_;
    } else if (rt <= M_) {                  // mems row rt-1
        tok_ptr = mems + (size_t)(rt - 1) * L_;
        dst = enc + (size_t)(rt - 1) * D_;  ai = rt - 1;
    } else if (rt == M_ + 1) {              // ys -> out_ys row 0
        tok_ptr = ys;  dst = out_ys;
    } else {                                // cands -> out_ys rows 1..4096
        const int c = rt - (M_ + 2);
        tok_ptr = cands + (size_t)c * L_;
        dst = out_ys + (size_t)(c + 1) * D_;
    }

    // encode own row
    int tok = 0; float w = 0.f;
    if (lane < L_) { tok = tok_ptr[lane]; w = freqs[tok]; }
    const float s2 = wave_allreduce_sum(w * w);
    const float wn = w / sqrtf(s2);         // freqs > 0 -> s2 > 0

    float4 acc = make_float4(0.f, 0.f, 0.f, 0.f);
    #pragma unroll
    for (int l = 0; l < L_; ++l) {
        const int t = __shfl(tok, l, 64);
        const float wl = __shfl(wn, l, 64);
        const float4 v = *reinterpret_cast<const float4*>(lt + (size_t)t * D_ + d0);
        acc.x += wl * v.x; acc.y += wl * v.y; acc.z += wl * v.z; acc.w += wl * v.w;
    }
    *reinterpret_cast<float4*>(dst + d0) = acc;

    if (ai >= 0) {
        // xs fragment (same 32 lt rows for all mems waves -> L2-broadcast)
        int txs = 0; float wxs = 0.f;
        if (lane < L_) { txs = xs[lane]; wxs = freqs[txs]; }
        const float sx = wave_allreduce_sum(wxs * wxs);
        const float wnx = wxs / sqrtf(sx);
        float4 xf = make_float4(0.f, 0.f, 0.f, 0.f);
        #pragma unroll
        for (int l = 0; l < L_; ++l) {
            const int t = __shfl(txs, l, 64);
            const float wl = __shfl(wnx, l, 64);
            const float4 v = *reinterpret_cast<const float4*>(lt + (size_t)t * D_ + d0);
            xf.x += wl * v.x; xf.y += wl * v.y; xf.z += wl * v.z; xf.w += wl * v.w;
        }
        const float an2 = wave_allreduce_sum(xf.x*xf.x + xf.y*xf.y + xf.z*xf.z + xf.w*xf.w);
        const float d  = wave_allreduce_sum(acc.x*xf.x + acc.y*xf.y + acc.z*xf.z + acc.w*xf.w);
        const float q  = wave_allreduce_sum(acc.x*acc.x + acc.y*acc.y + acc.z*acc.z + acc.w*acc.w);
        if (lane == 0) {
            const float an = fmaxf(sqrtf(an2), 1e-8f);
            const float bn = fmaxf(sqrtf(q),  1e-8f);
            att[ai] = expf(d / (an * bn));
        }
    }
}

// ---------------------------------------------------------------------------
// K2: blocks 0..15 -> part[b][t] = sum over 256(+1) rows of att[i]*enc[i][t]
//     block 16     -> gsum = sum(att)
// ---------------------------------------------------------------------------
__global__ __launch_bounds__(256) void lhs_partial(
    const float* __restrict__ enc, const float* __restrict__ att,
    float* __restrict__ part,     // [16, 256]
    float* __restrict__ gsum)     // [1]
{
    const int t = threadIdx.x;
    if (blockIdx.x < NCHUNK) {
        const int i0 = blockIdx.x * 256;
        const int i1 = (blockIdx.x == NCHUNK - 1) ? ROWS_MEMS : i0 + 256;
        float a = 0.f;
        for (int i = i0; i < i1; ++i) a += att[i] * enc[(size_t)i * D_ + t];
        part[(size_t)blockIdx.x * D_ + t] = a;
    } else {
        __shared__ float red[4];
        float s = 0.f;
        for (int i = t; i < ROWS_MEMS; i += 256) s += att[i];
        s = wave_allreduce_sum(s);
        const int wave = t >> 6, lane = t & 63;
        if (lane == 0) red[wave] = s;
        __syncthreads();
        if (t == 0) *gsum = red[0] + red[1] + red[2] + red[3];
    }
}

// ---------------------------------------------------------------------------
// K3: fold the 16 partials, normalize by gsum, tile into out_xs rows
// ---------------------------------------------------------------------------
__global__ __launch_bounds__(256) void tile_out(
    const float* __restrict__ part, const float* __restrict__ gsum,
    float* __restrict__ out_xs)
{
    const int t = threadIdx.x;
    float a = 0.f;
    #pragma unroll
    for (int k = 0; k < NCHUNK; ++k) a += part[(size_t)k * D_ + t];
    const float val = a / gsum[0];
    for (int r = blockIdx.x; r < ROWS_MEMS; r += gridDim.x)
        out_xs[(size_t)r * D_ + t] = val;
}

extern "C" void kernel_launch(void* const* d_in, const int* in_sizes, int n_in,
                              void* d_out, int out_size, void* d_ws, size_t ws_size,
                              hipStream_t stream) {
    const int*   xs    = (const int*)d_in[0];
    const int*   mems  = (const int*)d_in[1];
    const int*   ys    = (const int*)d_in[2];
    const int*   cands = (const int*)d_in[3];
    const float* lt    = (const float*)d_in[4];
    const float* freqs = (const float*)d_in[5];

    float* out    = (float*)d_out;
    float* out_xs = out;                                   // [4097, 256]
    float* out_ys = out + (size_t)ROWS_MEMS * D_;          // [4097, 256]

    // ws layout (floats): enc[4097*256] | att[4097] | part[16*256] | gsum[1]
    float* enc  = (float*)d_ws;
    float* att  = enc + (size_t)ROWS_MEMS * D_;
    float* part = att + ROWS_MEMS;
    float* gsum = part + (size_t)NCHUNK * D_;

    encode_att<<<(NTASK + 3) / 4, 256, 0, stream>>>(xs, mems, ys, cands, lt, freqs,
                                                    enc, att, out_ys);
    lhs_partial<<<NCHUNK + 1, 256, 0, stream>>>(enc, att, part, gsum);
    tile_out<<<1024, 256, 0, stream>>>(part, gsum, out_xs);
}

// Round 4
// 188.513 us; speedup vs baseline: 1.2574x; 1.2574x over previous
//
#include <hip/hip_runtime.h>

// Problem constants (match reference)
#define V_ 100000
#define D_ 256
#define M_ 4096
#define C_ 4096
#define L_ 32
#define ROWS_MEMS (M_ + 1)          // 4097 rows in mems_enc (mems + xs_emb)
#define NTASK (1 + M_ + 1 + C_)     // 8194 encode row-tasks

__device__ __forceinline__ float wave_allreduce_sum(float v) {
    #pragma unroll
    for (int off = 32; off >= 1; off >>= 1) v += __shfl_xor(v, off, 64);
    return v;
}

// ---------------------------------------------------------------------------
// K1: fully fused encode + attention + weighted accumulation.
//   One wave per row-task, 4 rows per 256-thread block (2049 blocks).
//   - ys/cands rows: encode -> write straight to out_ys.
//   - mems/xs rows: encode in registers, e = exp(cos(row, xs)) (cos in [-1,1]
//     so no max-subtraction needed), then accumulate e*row into an LDS
//     block-partial and e into a block e-sum; one global atomicAdd per thread
//     per block combines partials (<=1025 adds/address, pipelined in L2).
//   The mems encodings are NEVER materialized in global memory.
// ---------------------------------------------------------------------------
__global__ __launch_bounds__(256) void encode_fused(
    const int* __restrict__ xs, const int* __restrict__ mems,
    const int* __restrict__ ys, const int* __restrict__ cands,
    const float* __restrict__ lt, const float* __restrict__ freqs,
    float* __restrict__ lhs_raw,   // [256], zeroed: sum_i e_i * row_i
    float* __restrict__ gsum,      // [1],  zeroed: sum_i e_i
    float* __restrict__ out_ys)    // d_out second half: [4097, 256]
{
    __shared__ float s_xf[D_];     // xs embedding fragment
    __shared__ float s_an2;        // ||xs||^2
    __shared__ float s_lred[D_];   // block partial of sum e*row
    __shared__ float s_ered;       // block partial of sum e

    const int wave = threadIdx.x >> 6;
    const int lane = threadIdx.x & 63;
    const int d0 = lane * 4;               // 64 lanes x 4 dims = 256
    const int rt0 = blockIdx.x * 4;
    const bool block_has_att = (rt0 <= M_);   // blocks 0..1024 carry att rows

    s_lred[threadIdx.x] = 0.f;
    if (threadIdx.x == 0) s_ered = 0.f;

    // wave 0 computes the xs fragment once per block (same 32 lt rows
    // everywhere -> L1/L2 broadcast)
    if (block_has_att && wave == 0) {
        int txs = 0; float wxs = 0.f;
        if (lane < L_) { txs = xs[lane]; wxs = freqs[txs]; }
        const float sx = wave_allreduce_sum(wxs * wxs);
        const float wnx = wxs / sqrtf(sx);
        float4 xf = make_float4(0.f, 0.f, 0.f, 0.f);
        #pragma unroll
        for (int l = 0; l < L_; ++l) {
            const int t = __shfl(txs, l, 64);
            const float wl = __shfl(wnx, l, 64);
            const float4 v = *reinterpret_cast<const float4*>(lt + (size_t)t * D_ + d0);
            xf.x += wl * v.x; xf.y += wl * v.y; xf.z += wl * v.z; xf.w += wl * v.w;
        }
        *reinterpret_cast<float4*>(&s_xf[d0]) = xf;
        const float an2 = wave_allreduce_sum(xf.x*xf.x + xf.y*xf.y + xf.z*xf.z + xf.w*xf.w);
        if (lane == 0) s_an2 = an2;
    }
    __syncthreads();

    const int rt = rt0 + wave;
    if (rt < NTASK) {
        const int* tok_ptr; float* dst = nullptr; bool has_att = false;
        if (rt == 0) {                       // xs row itself
            tok_ptr = xs; has_att = true;
        } else if (rt <= M_) {               // mems row rt-1
            tok_ptr = mems + (size_t)(rt - 1) * L_; has_att = true;
        } else if (rt == M_ + 1) {           // ys -> out_ys row 0
            tok_ptr = ys; dst = out_ys;
        } else {                             // cands -> out_ys rows 1..4096
            const int c = rt - (M_ + 2);
            tok_ptr = cands + (size_t)c * L_;
            dst = out_ys + (size_t)(c + 1) * D_;
        }

        int tok = 0; float w = 0.f;
        if (lane < L_) { tok = tok_ptr[lane]; w = freqs[tok]; }
        const float s2 = wave_allreduce_sum(w * w);
        const float wn = w / sqrtf(s2);      // freqs > 0 -> s2 > 0

        float4 acc = make_float4(0.f, 0.f, 0.f, 0.f);
        #pragma unroll
        for (int l = 0; l < L_; ++l) {
            const int t = __shfl(tok, l, 64);
            const float wl = __shfl(wn, l, 64);
            const float4 v = *reinterpret_cast<const float4*>(lt + (size_t)t * D_ + d0);
            acc.x += wl * v.x; acc.y += wl * v.y; acc.z += wl * v.z; acc.w += wl * v.w;
        }

        if (has_att) {
            const float4 xf = *reinterpret_cast<const float4*>(&s_xf[d0]);
            const float d = wave_allreduce_sum(acc.x*xf.x + acc.y*xf.y + acc.z*xf.z + acc.w*xf.w);
            const float q = wave_allreduce_sum(acc.x*acc.x + acc.y*acc.y + acc.z*acc.z + acc.w*acc.w);
            const float an = fmaxf(sqrtf(s_an2), 1e-8f);
            const float bn = fmaxf(sqrtf(q),  1e-8f);
            const float e = expf(d / (an * bn));     // same value on all lanes
            atomicAdd(&s_lred[d0 + 0], e * acc.x);   // LDS atomics: 4-wave combine
            atomicAdd(&s_lred[d0 + 1], e * acc.y);
            atomicAdd(&s_lred[d0 + 2], e * acc.z);
            atomicAdd(&s_lred[d0 + 3], e * acc.w);
            if (lane == 0) atomicAdd(&s_ered, e);
        } else {
            *reinterpret_cast<float4*>(dst + d0) = acc;
        }
    }

    if (block_has_att) {
        __syncthreads();
        atomicAdd(&lhs_raw[threadIdx.x], s_lred[threadIdx.x]);
        if (threadIdx.x == 0) atomicAdd(gsum, s_ered);
    }
}

// ---------------------------------------------------------------------------
// K2: normalize lhs by the softmax denominator and tile into out_xs rows.
// ---------------------------------------------------------------------------
__global__ __launch_bounds__(256) void finalize_tile(
    const float* __restrict__ lhs_raw, const float* __restrict__ gsum,
    float* __restrict__ out_xs)
{
    const float val = lhs_raw[threadIdx.x] / gsum[0];
    for (int r = blockIdx.x; r < ROWS_MEMS; r += gridDim.x)
        out_xs[(size_t)r * D_ + threadIdx.x] = val;
}

extern "C" void kernel_launch(void* const* d_in, const int* in_sizes, int n_in,
                              void* d_out, int out_size, void* d_ws, size_t ws_size,
                              hipStream_t stream) {
    const int*   xs    = (const int*)d_in[0];
    const int*   mems  = (const int*)d_in[1];
    const int*   ys    = (const int*)d_in[2];
    const int*   cands = (const int*)d_in[3];
    const float* lt    = (const float*)d_in[4];
    const float* freqs = (const float*)d_in[5];

    float* out    = (float*)d_out;
    float* out_xs = out;                                   // [4097, 256]
    float* out_ys = out + (size_t)ROWS_MEMS * D_;          // [4097, 256]

    // ws layout (floats): lhs_raw[256] | gsum[1]
    float* lhs_raw = (float*)d_ws;
    float* gsum    = lhs_raw + D_;

    hipMemsetAsync(lhs_raw, 0, (D_ + 1) * sizeof(float), stream);

    encode_fused<<<(NTASK + 3) / 4, 256, 0, stream>>>(xs, mems, ys, cands, lt, freqs,
                                                      lhs_raw, gsum, out_ys);
    finalize_tile<<<1024, 256, 0, stream>>>(lhs_raw, gsum, out_xs);
}